// Round 1
// baseline (238.734 us; speedup 1.0000x reference)
//
#include <hip/hip_runtime.h>

typedef __attribute__((ext_vector_type(8))) short short8;
typedef __attribute__((ext_vector_type(4))) float f32x4;

// Pack two fp32 into two bf16 (round-half-up) in one u32: 3 VALU ops per pair.
__device__ __forceinline__ unsigned pack2bf(float x0, float x1) {
    unsigned u0 = __float_as_uint(x0) + 0x8000u;
    unsigned u1 = __float_as_uint(x1) + 0x8000u;
    // out.lo16 = u0.hi16, out.hi16 = u1.hi16
    return __builtin_amdgcn_perm(u1, u0, 0x07060302u);
}

// Convert W (mul x mul, row-major [u][w]) to bf16, fold in scale, and store in
// MFMA-B-fragment order: frag (cb,kb) holds B[k][n] for n=cb*16+(l&15),
// k=kb*32+(l>>4)*8+j ; element addr = ((cb*NKB+kb)*64 + lane)*8 + j.
__global__ __launch_bounds__(256) void prep_w(const float* __restrict__ W,
                                              unsigned short* __restrict__ dst,
                                              int mul, float scale) {
    int idx = blockIdx.x * 256 + threadIdx.x;
    if (idx >= mul * mul) return;
    int u = idx >> (mul == 256 ? 8 : (mul == 128 ? 7 : 6));
    int w = idx - u * mul;
    int nkb = mul >> 5;
    int cb = w >> 4, kb = u >> 5;
    int lane = ((u >> 3) & 3) * 16 + (w & 15);
    int j = u & 7;
    unsigned uv = __float_as_uint(W[idx] * scale) + 0x8000u;
    dst[(((cb * nkb + kb) * 64 + lane) << 3) + j] = (unsigned short)(uv >> 16);
}

// One irrep block: out[b, OFF + w*D + d] = sum_u in[b, OFF + u*D + d] * Wscaled[u,w]
// Wave handles 32 rows (2 subtiles of 16) so each B fragment is reused 2*D times.
template <int MUL, int D, int OFF, bool BIAS>
__device__ __forceinline__ void do_block(const float* __restrict__ inA0,  // row (rbase+lm)
                                         float* __restrict__ outb,        // out + rbase*960
                                         const unsigned short* __restrict__ wf,
                                         int lm, int lg, int lane,
                                         const float* __restrict__ bias) {
    constexpr int NKB = MUL / 32;  // k-blocks of 32
    constexpr int NCB = MUL / 16;  // col-blocks of 16
    short8 a[2][D][NKB];
    // ---- A fragments: contiguous loads (u-octet x all d), de-interleave in regs
#pragma unroll
    for (int s = 0; s < 2; ++s) {
        const float* rowp = inA0 + s * 16 * 960 + OFF;
#pragma unroll
        for (int kb = 0; kb < NKB; ++kb) {
            float buf[8 * D];
            const float* p = rowp + (kb * 32 + lg * 8) * D;
#pragma unroll
            for (int v = 0; v < 2 * D; ++v) {
                f32x4 t = *reinterpret_cast<const f32x4*>(p + v * 4);
                buf[v * 4 + 0] = t[0]; buf[v * 4 + 1] = t[1];
                buf[v * 4 + 2] = t[2]; buf[v * 4 + 3] = t[3];
            }
#pragma unroll
            for (int d = 0; d < D; ++d) {
                union { short8 s8; unsigned u32[4]; } fr;
#pragma unroll
                for (int jj = 0; jj < 4; ++jj)
                    fr.u32[jj] = pack2bf(buf[(2 * jj) * D + d], buf[(2 * jj + 1) * D + d]);
                a[s][d][kb] = fr.s8;
            }
        }
    }
    // ---- per col-block: load B frags once, use for 2 subtiles x D
#pragma unroll 1
    for (int cb = 0; cb < NCB; ++cb) {
        short8 bfr[NKB];
#pragma unroll
        for (int kb = 0; kb < NKB; ++kb)
            bfr[kb] = *reinterpret_cast<const short8*>(wf + (((cb * NKB + kb) * 64 + lane) << 3));
        float bv = BIAS ? bias[cb * 16 + lm] : 0.0f;
#pragma unroll
        for (int s = 0; s < 2; ++s) {
            f32x4 acc[D];
#pragma unroll
            for (int d = 0; d < D; ++d) {
                f32x4 z = {0.0f, 0.0f, 0.0f, 0.0f};
#pragma unroll
                for (int kb = 0; kb < NKB; ++kb)
                    z = __builtin_amdgcn_mfma_f32_16x16x32_bf16(a[s][d][kb], bfr[kb], z, 0, 0, 0);
                acc[d] = z;
            }
            // D/C layout: col = lane&15, row = (lane>>4)*4 + reg  (m89-verified)
#pragma unroll
            for (int jj = 0; jj < 4; ++jj) {
                float* op = outb + (s * 16 + lg * 4 + jj) * 960 + OFF + (cb * 16 + lm) * D;
#pragma unroll
                for (int d = 0; d < D; ++d)
                    op[d] = BIAS ? (acc[d][jj] + bv) : acc[d][jj];
            }
        }
    }
}

__global__ __launch_bounds__(256, 3) void lin_main(const float* __restrict__ in,
                                                   const unsigned short* __restrict__ wf0,
                                                   const unsigned short* __restrict__ wf1,
                                                   const unsigned short* __restrict__ wf2,
                                                   const float* __restrict__ bias,
                                                   float* __restrict__ out) {
    int wid = blockIdx.x * 4 + (threadIdx.x >> 6);
    if (wid >= 3125) return;  // 100000 rows / 32 per wave
    int lane = threadIdx.x & 63;
    int lm = lane & 15, lg = lane >> 4;
    int rbase = wid * 32;
    const float* inA0 = in + (size_t)(rbase + lm) * 960;
    float* outb = out + (size_t)rbase * 960;
    do_block<256, 1, 0, true >(inA0, outb, wf0, lm, lg, lane, bias);
    do_block<128, 3, 256, false>(inA0, outb, wf1, lm, lg, lane, nullptr);
    do_block<64, 5, 640, false>(inA0, outb, wf2, lm, lg, lane, nullptr);
}

extern "C" void kernel_launch(void* const* d_in, const int* in_sizes, int n_in,
                              void* d_out, int out_size, void* d_ws, size_t ws_size,
                              hipStream_t stream) {
    (void)in_sizes; (void)n_in; (void)out_size; (void)ws_size;
    const float* x  = (const float*)d_in[0];
    const float* W0 = (const float*)d_in[1];
    const float* W1 = (const float*)d_in[2];
    const float* W2 = (const float*)d_in[3];
    const float* b  = (const float*)d_in[4];
    float* out = (float*)d_out;
    unsigned short* wf = (unsigned short*)d_ws;  // 65536 + 16384 + 4096 bf16 = 168 KB

    prep_w<<<256, 256, 0, stream>>>(W0, wf,         256, 0.0625f);               // 1/sqrt(256)
    prep_w<<<64,  256, 0, stream>>>(W1, wf + 65536, 128, 0.08838834764831845f);  // 1/sqrt(128)
    prep_w<<<16,  256, 0, stream>>>(W2, wf + 81920, 64,  0.125f);                // 1/sqrt(64)
    lin_main<<<782, 256, 0, stream>>>(x, wf, wf + 65536, wf + 81920, b, out);
}

// Round 2
// 206.511 us; speedup vs baseline: 1.1560x; 1.1560x over previous
//
#include <hip/hip_runtime.h>

typedef __attribute__((ext_vector_type(8))) short short8;
typedef __attribute__((ext_vector_type(4))) float f32x4;

// Pack two fp32 into two bf16 (round-half-up) in one u32: 3 VALU ops per pair.
__device__ __forceinline__ unsigned pack2bf(float x0, float x1) {
    unsigned u0 = __float_as_uint(x0) + 0x8000u;
    unsigned u1 = __float_as_uint(x1) + 0x8000u;
    // out.lo16 = u0.hi16, out.hi16 = u1.hi16
    return __builtin_amdgcn_perm(u1, u0, 0x07060302u);
}

// Convert W (mul x mul, row-major [u][w]) to bf16, fold in scale, and store in
// MFMA-B-fragment order: frag (cb,kb) holds B[k][n] for n=cb*16+(l&15),
// k=kb*32+(l>>4)*8+j ; element addr = ((cb*NKB+kb)*64 + lane)*8 + j.
__global__ __launch_bounds__(256) void prep_w(const float* __restrict__ W,
                                              unsigned short* __restrict__ dst,
                                              int mul, float scale) {
    int idx = blockIdx.x * 256 + threadIdx.x;
    if (idx >= mul * mul) return;
    int u = idx >> (mul == 256 ? 8 : (mul == 128 ? 7 : 6));
    int w = idx - u * mul;
    int nkb = mul >> 5;
    int cb = w >> 4, kb = u >> 5;
    int lane = ((u >> 3) & 3) * 16 + (w & 15);
    int j = u & 7;
    unsigned uv = __float_as_uint(W[idx] * scale) + 0x8000u;
    dst[(((cb * nkb + kb) * 64 + lane) << 3) + j] = (unsigned short)(uv >> 16);
}

// One irrep block: out[b, OFF + w*D + d] = sum_u in[b, OFF + u*D + d] * Wscaled[u,w]
// Wave handles 16 rows (one M-subtile). cb loop unrolled x2 so next
// iteration's B-loads pipeline with current iteration's MFMAs.
template <int MUL, int D, int OFF, bool BIAS>
__device__ __forceinline__ void do_block(const float* __restrict__ inA0,  // row (rbase+lm)
                                         float* __restrict__ outb,        // out + rbase*960
                                         const unsigned short* __restrict__ wf,
                                         int lm, int lg, int lane,
                                         const float* __restrict__ bias) {
    constexpr int NKB = MUL / 32;  // k-blocks of 32
    constexpr int NCB = MUL / 16;  // col-blocks of 16
    short8 a[D][NKB];
    // ---- A fragments: contiguous loads (u-octet x all d), de-interleave in regs
    const float* rowp = inA0 + OFF;
#pragma unroll
    for (int kb = 0; kb < NKB; ++kb) {
        float buf[8 * D];
        const float* p = rowp + (kb * 32 + lg * 8) * D;
#pragma unroll
        for (int v = 0; v < 2 * D; ++v) {
            f32x4 t = *reinterpret_cast<const f32x4*>(p + v * 4);
            buf[v * 4 + 0] = t[0]; buf[v * 4 + 1] = t[1];
            buf[v * 4 + 2] = t[2]; buf[v * 4 + 3] = t[3];
        }
#pragma unroll
        for (int d = 0; d < D; ++d) {
            union { short8 s8; unsigned u32[4]; } fr;
#pragma unroll
            for (int jj = 0; jj < 4; ++jj)
                fr.u32[jj] = pack2bf(buf[(2 * jj) * D + d], buf[(2 * jj + 1) * D + d]);
            a[d][kb] = fr.s8;
        }
    }
    // ---- per col-block: load B frags once, use for D MFMAs per kb
#pragma unroll 2
    for (int cb = 0; cb < NCB; ++cb) {
        short8 bfr[NKB];
#pragma unroll
        for (int kb = 0; kb < NKB; ++kb)
            bfr[kb] = *reinterpret_cast<const short8*>(wf + (((cb * NKB + kb) * 64 + lane) << 3));
        float bv = BIAS ? bias[cb * 16 + lm] : 0.0f;
        f32x4 acc[D];
#pragma unroll
        for (int d = 0; d < D; ++d) {
            f32x4 z = {0.0f, 0.0f, 0.0f, 0.0f};
#pragma unroll
            for (int kb = 0; kb < NKB; ++kb)
                z = __builtin_amdgcn_mfma_f32_16x16x32_bf16(a[d][kb], bfr[kb], z, 0, 0, 0);
            acc[d] = z;
        }
        // D/C layout: col = lane&15, row = (lane>>4)*4 + reg  (m89-verified)
#pragma unroll
        for (int jj = 0; jj < 4; ++jj) {
            float* op = outb + (lg * 4 + jj) * 960 + OFF + (cb * 16 + lm) * D;
#pragma unroll
            for (int d = 0; d < D; ++d)
                op[d] = BIAS ? (acc[d][jj] + bv) : acc[d][jj];
        }
    }
}

__global__ __launch_bounds__(256, 4) void lin_main(const float* __restrict__ in,
                                                   const unsigned short* __restrict__ wf0,
                                                   const unsigned short* __restrict__ wf1,
                                                   const unsigned short* __restrict__ wf2,
                                                   const float* __restrict__ bias,
                                                   float* __restrict__ out) {
    int wid = blockIdx.x * 4 + (threadIdx.x >> 6);
    if (wid >= 6250) return;  // 100000 rows / 16 per wave
    int lane = threadIdx.x & 63;
    int lm = lane & 15, lg = lane >> 4;
    int rbase = wid * 16;
    const float* inA0 = in + (size_t)(rbase + lm) * 960;
    float* outb = out + (size_t)rbase * 960;
    do_block<256, 1, 0, true >(inA0, outb, wf0, lm, lg, lane, bias);
    do_block<128, 3, 256, false>(inA0, outb, wf1, lm, lg, lane, nullptr);
    do_block<64, 5, 640, false>(inA0, outb, wf2, lm, lg, lane, nullptr);
}

extern "C" void kernel_launch(void* const* d_in, const int* in_sizes, int n_in,
                              void* d_out, int out_size, void* d_ws, size_t ws_size,
                              hipStream_t stream) {
    (void)in_sizes; (void)n_in; (void)out_size; (void)ws_size;
    const float* x  = (const float*)d_in[0];
    const float* W0 = (const float*)d_in[1];
    const float* W1 = (const float*)d_in[2];
    const float* W2 = (const float*)d_in[3];
    const float* b  = (const float*)d_in[4];
    float* out = (float*)d_out;
    unsigned short* wf = (unsigned short*)d_ws;  // 65536 + 16384 + 4096 bf16 = 168 KB

    prep_w<<<256, 256, 0, stream>>>(W0, wf,         256, 0.0625f);               // 1/sqrt(256)
    prep_w<<<64,  256, 0, stream>>>(W1, wf + 65536, 128, 0.08838834764831845f);  // 1/sqrt(128)
    prep_w<<<16,  256, 0, stream>>>(W2, wf + 81920, 64,  0.125f);                // 1/sqrt(64)
    lin_main<<<1563, 256, 0, stream>>>(x, wf, wf + 65536, wf + 81920, b, out);
}